// Round 10
// baseline (836.034 us; speedup 1.0000x reference)
//
#include <hip/hip_runtime.h>
#include <hip/hip_bf16.h>
#include <cstdint>
#include <cstddef>

#define HIDDEN_ 4096
#define NHEAD 32
#define HDIM 128
#define SEQ 2048
#define BATCH 2
#define MROWS (BATCH * SEQ)      // 4096
#define QKVN (3 * HIDDEN_)       // 12288

typedef __bf16 bf16;
typedef __bf16 bf16x8 __attribute__((ext_vector_type(8)));
typedef float f32x4 __attribute__((ext_vector_type(4)));
typedef float f32x16 __attribute__((ext_vector_type(16)));

#define AS1 __attribute__((address_space(1)))
#define AS3 __attribute__((address_space(3)))
#define PH_BAR do { asm volatile("" ::: "memory"); __builtin_amdgcn_s_barrier(); asm volatile("" ::: "memory"); } while (0)
#define MFMA32_(d, a_, b_) (d) = __builtin_amdgcn_mfma_f32_32x32x16_bf16((a_), (b_), (d), 0, 0, 0)

// ---------------- cast fp32 -> bf16, 8 elems/thread ----------------
__global__ __launch_bounds__(256) void cast_bf16_k(const float* __restrict__ in,
                                                   bf16* __restrict__ out, int n) {
  int i = (blockIdx.x * 256 + threadIdx.x) * 8;
  if (i >= n) return;
  f32x4 a = *(const f32x4*)(in + i);
  f32x4 b = *(const f32x4*)(in + i + 4);
  bf16x8 o;
  o[0] = (bf16)a[0]; o[1] = (bf16)a[1]; o[2] = (bf16)a[2]; o[3] = (bf16)a[3];
  o[4] = (bf16)b[0]; o[5] = (bf16)b[1]; o[6] = (bf16)b[2]; o[7] = (bf16)b[3];
  *(bf16x8*)(out + i) = o;
}

// ---------------- transpose + cast: in[R][C] fp32 -> out[C][R] bf16 ----------------
__global__ __launch_bounds__(256) void transpose_cast_k(const float* __restrict__ in,
                                                        bf16* __restrict__ out,
                                                        int R, int C) {
  __shared__ float tile[32][33];
  int c0 = blockIdx.x * 32, r0 = blockIdx.y * 32;
  int tx = threadIdx.x & 31, ty = threadIdx.x >> 5;  // 32 x 8
#pragma unroll
  for (int i = 0; i < 4; i++) {
    int r = ty + i * 8;
    tile[r][tx] = in[(size_t)(r0 + r) * C + (c0 + tx)];
  }
  __syncthreads();
#pragma unroll
  for (int i = 0; i < 4; i++) {
    int r = ty + i * 8;
    out[(size_t)(c0 + r) * R + (r0 + tx)] = (bf16)tile[tx][r];
  }
}

// ---------------- 256x256 4-phase GEMM with 32x32x16 MFMA ----------------
// Round-6 structure (best measured: 400us) with the MFMA shape switched to
// 32x32x16: half the MFMA instructions (32/K-tile/wave), +15% ubench rate
// (2382 vs 2075 TF), fewer live operand regs. Schedule proven insensitive
// (rounds 3-9), so only the shape + fragment/epilogue mapping changes.
//
// 512 threads = 8 waves (2M x 4N), per-wave C = 128x64 = acc[4][2] f32x16.
// A-frag: row=lane&31, kbyte = ks*32 + (lane>>5)*16 (identical mapping for B
// so k-permutations cancel). C/D: col=lane&31, row=(reg&3)+8*(reg>>2)+4*(lane>>5)
// [HW-verified m74/m101]. LDS: A0/A1/B0/B1 [256][64] bf16, XOR swizzle
// (byte ^= (row&7)<<4) via pre-swizzled global source + swizzled ds_read.
// 4 phases/iter, stages quarter-audited (round-6 slots), vmcnt(4) at ph23/ph67.
template <int EPI>
__global__ __launch_bounds__(512, 2) void gemm256_k(
    const bf16* __restrict__ A, const bf16* __restrict__ BT,
    const float* __restrict__ bias, float* __restrict__ outF,
    bf16* __restrict__ Qb, bf16* __restrict__ Kb, bf16* __restrict__ Vt,
    int M, int N, int K, int nbx) {
  __shared__ char lds[131072];
  char* const A0 = lds;             // buf0 A (even K-tiles), 32 KB = [256][64] bf16
  char* const A1 = lds + 32768;     // buf1 A (odd K-tiles)
  char* const B0 = lds + 65536;     // buf0 B
  char* const B1 = lds + 98304;     // buf1 B

  const int tid = threadIdx.x;
  const int w = tid >> 6, l = tid & 63;
  const int l31 = l & 31, hi = l >> 5;
  const int wm = (w >> 2) * 128;    // wave M offset within tile
  const int wn = (w & 3) * 64;      // wave N offset within tile

  // bijective XCD swizzle (gridDim.x % 8 == 0)
  const int cpx = (int)gridDim.x >> 3;
  const int bid = blockIdx.x;
  const int swz = (bid & 7) * cpx + (bid >> 3);
  const int bx = swz % nbx, by = swz / nbx;
  const int m0 = by * 256, n0 = bx * 256;

  const int NT = K >> 6;   // 64-wide K tiles
  const int NI = K >> 7;   // iterations (2 tiles each)

  // ---- hoisted global stage pointers (per half, per chunk) ----
  const bf16* gA[2][2]; const bf16* gB[2][2];
#pragma unroll
  for (int half = 0; half < 2; ++half)
#pragma unroll
    for (int i = 0; i < 2; ++i) {
      const int ci = i * 512 + tid;
      const int r = ci >> 3;
      const int cb = ((ci & 7) << 4) ^ ((r & 7) << 4);
      gA[half][i] = A + (size_t)(m0 + half * 128 + r) * K + (cb >> 1);
      gB[half][i] = BT + (size_t)(n0 + half * 128 + r) * K + (cb >> 1);
    }

  // ---- hoisted LDS read byte-offsets (32x32 fragments) ----
  int offA[4][4], offB[2][4];
#pragma unroll
  for (int mf = 0; mf < 4; ++mf) {
    const int r = wm + mf * 32 + l31;
#pragma unroll
    for (int ks = 0; ks < 4; ++ks)
      offA[mf][ks] = r * 128 + ((ks * 32 + hi * 16) ^ ((r & 7) << 4));
  }
#pragma unroll
  for (int nf = 0; nf < 2; ++nf) {
    const int r = wn + nf * 32 + l31;
#pragma unroll
    for (int ks = 0; ks < 4; ++ks)
      offB[nf][ks] = r * 128 + ((ks * 32 + hi * 16) ^ ((r & 7) << 4));
  }

  auto stageA = [&](char* buf, int half, int kt) {
#pragma unroll
    for (int i = 0; i < 2; ++i) {
      const int ci = i * 512 + tid;
      __builtin_amdgcn_global_load_lds((const AS1 void*)(gA[half][i] + kt * 64),
                                       (AS3 void*)(buf + half * 16384 + ci * 16), 16, 0, 0);
    }
  };
  auto stageB = [&](char* buf, int half, int kt) {
#pragma unroll
    for (int i = 0; i < 2; ++i) {
      const int ci = i * 512 + tid;
      __builtin_amdgcn_global_load_lds((const AS1 void*)(gB[half][i] + kt * 64),
                                       (AS3 void*)(buf + half * 16384 + ci * 16), 16, 0, 0);
    }
  };

  f32x16 acc[4][2] = {};
  bf16x8 aLo[2][4], aHi[2][4], bAll[2][4];

  // ---- prologue: tile0 (8 ops) -> buf0, then B1 of tile1 (4 ops); vmcnt(4) drains tile0 ----
  stageA(A0, 0, 0); stageB(B0, 0, 0); stageA(A0, 1, 0); stageB(B0, 1, 0);
  stageB(B1, 0, 1); stageB(B1, 1, 1);
  asm volatile("s_waitcnt vmcnt(4)" ::: "memory");   // tile0 landed, B1(t1) in flight
  PH_BAR;

  for (int j = 0; j < NI; ++j) {
    const int tw = (2 * j + 1) & (NT - 1);   // odd tile -> buf1
    const int tu = (2 * j + 2) & (NT - 1);   // next even tile -> buf0
    const int tv = (2 * j + 3) & (NT - 1);   // next odd tile  -> buf1

    // ---- ph01: reads A0 rows 0-63/128-191 (mf 0-1) + B0 all; stage A1<-tw; 16 MFMA ----
#pragma unroll
    for (int mf = 0; mf < 2; ++mf)
#pragma unroll
      for (int ks = 0; ks < 4; ++ks) aLo[mf][ks] = *(const bf16x8*)(A0 + offA[mf][ks]);
#pragma unroll
    for (int nf = 0; nf < 2; ++nf)
#pragma unroll
      for (int ks = 0; ks < 4; ++ks) bAll[nf][ks] = *(const bf16x8*)(B0 + offB[nf][ks]);
    stageA(A1, 0, tw);
    stageA(A1, 1, tw);
    __builtin_amdgcn_s_setprio(1);
#pragma unroll
    for (int ks = 0; ks < 4; ++ks)
#pragma unroll
      for (int mf = 0; mf < 2; ++mf)
#pragma unroll
        for (int nf = 0; nf < 2; ++nf) MFMA32_(acc[mf][nf], aLo[mf][ks], bAll[nf][ks]);
    __builtin_amdgcn_s_setprio(0);
    PH_BAR;

    // ---- ph23: reads A0 rows 64-127/192-255 (mf 2-3); stage B0<-tu; 16 MFMA; vmcnt(4) ----
#pragma unroll
    for (int mf = 0; mf < 2; ++mf)
#pragma unroll
      for (int ks = 0; ks < 4; ++ks) aHi[mf][ks] = *(const bf16x8*)(A0 + offA[2 + mf][ks]);
    stageB(B0, 0, tu);
    stageB(B0, 1, tu);
    __builtin_amdgcn_s_setprio(1);
#pragma unroll
    for (int ks = 0; ks < 4; ++ks)
#pragma unroll
      for (int mf = 0; mf < 2; ++mf)
#pragma unroll
        for (int nf = 0; nf < 2; ++nf) MFMA32_(acc[2 + mf][nf], aHi[mf][ks], bAll[nf][ks]);
    __builtin_amdgcn_s_setprio(0);
    asm volatile("s_waitcnt vmcnt(4)" ::: "memory");  // A1(tw) resident; B0(tu) in flight
    PH_BAR;

    // ---- ph45: reads A1 mf 0-1 + B1 all; stage A0<-tu; 16 MFMA ----
#pragma unroll
    for (int mf = 0; mf < 2; ++mf)
#pragma unroll
      for (int ks = 0; ks < 4; ++ks) aLo[mf][ks] = *(const bf16x8*)(A1 + offA[mf][ks]);
#pragma unroll
    for (int nf = 0; nf < 2; ++nf)
#pragma unroll
      for (int ks = 0; ks < 4; ++ks) bAll[nf][ks] = *(const bf16x8*)(B1 + offB[nf][ks]);
    stageA(A0, 0, tu);
    stageA(A0, 1, tu);
    __builtin_amdgcn_s_setprio(1);
#pragma unroll
    for (int ks = 0; ks < 4; ++ks)
#pragma unroll
      for (int mf = 0; mf < 2; ++mf)
#pragma unroll
        for (int nf = 0; nf < 2; ++nf) MFMA32_(acc[mf][nf], aLo[mf][ks], bAll[nf][ks]);
    __builtin_amdgcn_s_setprio(0);
    PH_BAR;

    // ---- ph67: reads A1 mf 2-3; stage B1<-tv; 16 MFMA; vmcnt(4) ----
#pragma unroll
    for (int mf = 0; mf < 2; ++mf)
#pragma unroll
      for (int ks = 0; ks < 4; ++ks) aHi[mf][ks] = *(const bf16x8*)(A1 + offA[2 + mf][ks]);
    stageB(B1, 0, tv);
    stageB(B1, 1, tv);
    __builtin_amdgcn_s_setprio(1);
#pragma unroll
    for (int ks = 0; ks < 4; ++ks)
#pragma unroll
      for (int mf = 0; mf < 2; ++mf)
#pragma unroll
        for (int nf = 0; nf < 2; ++nf) MFMA32_(acc[2 + mf][nf], aHi[mf][ks], bAll[nf][ks]);
    __builtin_amdgcn_s_setprio(0);
    asm volatile("s_waitcnt vmcnt(4)" ::: "memory");  // B0+A0 (tu) resident; B1(tv) in flight
    PH_BAR;
  }

  // ---- epilogue: bias + store/scatter (32x32 C/D layout) ----
#pragma unroll
  for (int mf = 0; mf < 4; ++mf) {
#pragma unroll
    for (int nf = 0; nf < 2; ++nf) {
      const int col = n0 + wn + nf * 32 + l31;
      const float bv = bias[col];
#pragma unroll
      for (int reg = 0; reg < 16; ++reg) {
        const int row = m0 + wm + mf * 32 + (reg & 3) + ((reg >> 2) << 3) + (hi << 2);
        const float v = acc[mf][nf][reg] + bv;
        if (EPI == 0) {
          const int which = col >> 12, rem = col & 4095;
          const int h = rem >> 7, d = rem & 127;
          const int b = row >> 11, s = row & 2047;
          const size_t bh = (size_t)b * NHEAD + h;
          if (which == 0)      Qb[(bh * SEQ + s) * HDIM + d] = (bf16)v;
          else if (which == 1) Kb[(bh * SEQ + s) * HDIM + d] = (bf16)v;
          else                 Vt[(bh * HDIM + d) * SEQ + s] = (bf16)v;
        } else {
          outF[(size_t)row * N + col] = v;
        }
      }
    }
  }
}

// ---------------- flash attention: LDS-staged, double-buffered, swizzled ----------------
__global__ __launch_bounds__(512, 2) void attn_k(const bf16* __restrict__ Qb,
                                                 const bf16* __restrict__ Kb,
                                                 const bf16* __restrict__ Vt,
                                                 bf16* __restrict__ ctx) {
  __shared__ bf16 Ks[2][64 * 128];   // 2 x 16 KB
  __shared__ bf16 Vs[2][128 * 64];   // 2 x 16 KB
  __shared__ bf16 Pl[8][16 * 64];    // 16 KB, per-wave P tile (swizzled)
  const int tid = threadIdx.x, w = tid >> 6, l = tid & 63;
  const int bid = blockIdx.x;
  const int qt = 15 - (bid >> 6);          // longest blocks first
  const int bh = bid & 63;
  const int h = bh & (NHEAD - 1), b = bh >> 5;
  const int qbase = qt * 128 + w * 16;
  const int nt = 2 * qt + 2;               // KV tiles of 64 covering rows < qt*128+128
  const float slope = exp2f(-0.25f * (float)(h + 1));
  const float scale = 1.0f / 128.0f;
  const int lg = l >> 4, cl = l & 15;

  const bf16* Qp = Qb + (size_t)bh * SEQ * HDIM;
  const bf16* Kp = Kb + (size_t)bh * SEQ * HDIM;
  const bf16* Vp = Vt + (size_t)bh * HDIM * SEQ;
  char* plb = (char*)&Pl[w][0];

  bf16x8 qf[4];
#pragma unroll
  for (int kb = 0; kb < 4; kb++)
    qf[kb] = *(const bf16x8*)&Qp[(size_t)(qbase + cl) * HDIM + kb * 32 + lg * 8];

  float mi[4], li[4];
#pragma unroll
  for (int r = 0; r < 4; r++) { mi[r] = -3.0e38f; li[r] = 0.0f; }
  f32x4 oacc[8] = {};

  auto stage = [&](int buf, int t) {
    const int kv0 = t * 64;
#pragma unroll
    for (int i = 0; i < 2; i++) {
      const int ci = i * 512 + tid;
      {  // K: 256B rows
        const int r = ci >> 4;
        const int cbl = ((ci & 15) << 4) ^ ((r & 7) << 4);
        const bf16* src = Kp + (size_t)(kv0 + r) * HDIM + (cbl >> 1);
        __builtin_amdgcn_global_load_lds(
            (const AS1 void*)src,
            (AS3 void*)((char*)&Ks[buf][0] + ci * 16), 16, 0, 0);
      }
      {  // V: 128B rows
        const int r = ci >> 3;
        const int cbl = ((ci & 7) << 4) ^ ((r & 7) << 4);
        const bf16* src = Vp + (size_t)r * SEQ + kv0 + (cbl >> 1);
        __builtin_amdgcn_global_load_lds(
            (const AS1 void*)src,
            (AS3 void*)((char*)&Vs[buf][0] + ci * 16), 16, 0, 0);
      }
    }
  };

  stage(0, 0);
  __syncthreads();

  for (int t = 0; t < nt; ++t) {
    const int cur = t & 1;
    if (t + 1 < nt) stage(cur ^ 1, t + 1);
    const int kv0 = t * 64;

    if (kv0 <= qbase + 15) {
      char* ksb = (char*)&Ks[cur][0];
      char* vsb = (char*)&Vs[cur][0];
      f32x4 sacc[4];
#pragma unroll
      for (int nb = 0; nb < 4; nb++) {
        f32x4 a = {};
#pragma unroll
        for (int kb = 0; kb < 4; kb++) {
          const int row = nb * 16 + cl;
          const int cb = (kb * 64 + lg * 16) ^ ((row & 7) << 4);
          bf16x8 kf = *(const bf16x8*)(ksb + row * 256 + cb);
          a = __builtin_amdgcn_mfma_f32_16x16x32_bf16(qf[kb], kf, a, 0, 0, 0);
        }
        sacc[nb] = a;
      }
      float pm[4], sv[4][4];
#pragma unroll
      for (int r = 0; r < 4; r++) pm[r] = -3.0e38f;
#pragma unroll
      for (int nb = 0; nb < 4; nb++) {
        const int kv = kv0 + nb * 16 + cl;
#pragma unroll
        for (int r = 0; r < 4; r++) {
          const int q = qbase + lg * 4 + r;
          float v = sacc[nb][r] * scale + slope * (float)(kv - q);
          v = (kv <= q) ? v : -3.0e38f;
          sv[nb][r] = v;
          pm[r] = fmaxf(pm[r], v);
        }
      }
#pragma unroll
      for (int r = 0; r < 4; r++) {
        pm[r] = fmaxf(pm[r], __shfl_xor(pm[r], 1));
        pm[r] = fmaxf(pm[r], __shfl_xor(pm[r], 2));
        pm[r] = fmaxf(pm[r], __shfl_xor(pm[r], 4));
        pm[r] = fmaxf(pm[r], __shfl_xor(pm[r], 8));
      }
      float alpha[4], rs[4];
#pragma unroll
      for (int r = 0; r < 4; r++) {
        const float nm = fmaxf(mi[r], pm[r]);
        alpha[r] = __expf(mi[r] - nm);
        mi[r] = nm;
        rs[r] = 0.0f;
      }
#pragma unroll
      for (int nb = 0; nb < 4; nb++) {
#pragma unroll
        for (int r = 0; r < 4; r++) {
          const float p = __expf(sv[nb][r] - mi[r]);
          rs[r] += p;
          const int row = lg * 4 + r;
          *(bf16*)(plb + row * 128 + ((((nb * 16 + cl) << 1)) ^ ((row & 7) << 4))) = (bf16)p;
        }
      }
#pragma unroll
      for (int r = 0; r < 4; r++) {
        rs[r] += __shfl_xor(rs[r], 1);
        rs[r] += __shfl_xor(rs[r], 2);
        rs[r] += __shfl_xor(rs[r], 4);
        rs[r] += __shfl_xor(rs[r], 8);
        li[r] = li[r] * alpha[r] + rs[r];
      }
#pragma unroll
      for (int db = 0; db < 8; db++)
#pragma unroll
        for (int r = 0; r < 4; r++) oacc[db][r] *= alpha[r];
      bf16x8 pa[2];
#pragma unroll
      for (int ks = 0; ks < 2; ks++) {
        const int cb = (ks * 64 + lg * 16) ^ ((cl & 7) << 4);
        pa[ks] = *(const bf16x8*)(plb + cl * 128 + cb);
      }
#pragma unroll
      for (int db = 0; db < 8; db++) {
        f32x4 o = oacc[db];
#pragma unroll
        for (int ks = 0; ks < 2; ks++) {
          const int row = db * 16 + cl;
          const int cb = (ks * 64 + lg * 16) ^ ((row & 7) << 4);
          bf16x8 vf = *(const bf16x8*)(vsb + row * 128 + cb);
          o = __builtin_amdgcn_mfma_f32_16x16x32_bf16(pa[ks], vf, o, 0, 0, 0);
        }
        oacc[db] = o;
      }
    }
    __syncthreads();
  }

  float inv[4];
#pragma unroll
  for (int r = 0; r < 4; r++) inv[r] = 1.0f / li[r];
#pragma unroll
  for (int db = 0; db < 8; db++) {
#pragma unroll
    for (int r = 0; r < 4; r++) {
      const int q = qbase + lg * 4 + r;
      ctx[((size_t)(b * SEQ + q)) * HIDDEN_ + h * HDIM + db * 16 + cl] = (bf16)(oacc[db][r] * inv[r]);
    }
  }
}

// ---------------- launcher ----------------
extern "C" void kernel_launch(void* const* d_in, const int* in_sizes, int n_in,
                              void* d_out, int out_size, void* d_ws, size_t ws_size,
                              hipStream_t stream) {
  const float* hs     = (const float*)d_in[0];
  const float* w_attn = (const float*)d_in[1];
  const float* b_attn = (const float*)d_in[2];
  const float* w_proj = (const float*)d_in[3];
  const float* b_proj = (const float*)d_in[4];
  float* out = (float*)d_out;

  char* ws = (char*)d_ws;
  bf16* Xb  = (bf16*)(ws + 0);           // [4096][4096]        33.5 MB
  bf16* WaT = (bf16*)(ws + 33554432);    // [12288][4096]      100.7 MB
  bf16* WpT = (bf16*)(ws + 134217728);   // [4096][4096]        33.5 MB
  bf16* Qb  = (bf16*)(ws + 167772160);   // [B,H,S,D]           33.5 MB
  bf16* Kb  = (bf16*)(ws + 201326592);   // [B,H,S,D]           33.5 MB
  bf16* Vt  = (bf16*)(ws + 234881024);   // [B,H,D,S]           33.5 MB
  bf16* ctx = (bf16*)(ws + 268435456);   // [4096][4096]        33.5 MB

  cast_bf16_k<<<(MROWS * HIDDEN_) / (256 * 8), 256, 0, stream>>>(hs, Xb, MROWS * HIDDEN_);
  transpose_cast_k<<<dim3(QKVN / 32, HIDDEN_ / 32), 256, 0, stream>>>(w_attn, WaT, HIDDEN_, QKVN);
  transpose_cast_k<<<dim3(HIDDEN_ / 32, HIDDEN_ / 32), 256, 0, stream>>>(w_proj, WpT, HIDDEN_, HIDDEN_);

  gemm256_k<0><<<dim3((QKVN / 256) * (MROWS / 256)), 512, 0, stream>>>(
      Xb, WaT, b_attn, nullptr, Qb, Kb, Vt, MROWS, QKVN, HIDDEN_, QKVN / 256);

  attn_k<<<16 * 64, 512, 0, stream>>>(Qb, Kb, Vt, ctx);

  gemm256_k<1><<<dim3((HIDDEN_ / 256) * (MROWS / 256)), 512, 0, stream>>>(
      ctx, WpT, b_proj, out, nullptr, nullptr, nullptr, MROWS, HIDDEN_, HIDDEN_, HIDDEN_ / 256);
}

// Round 11
// 758.686 us; speedup vs baseline: 1.1020x; 1.1020x over previous
//
#include <hip/hip_runtime.h>
#include <hip/hip_bf16.h>
#include <cstdint>
#include <cstddef>

#define HIDDEN_ 4096
#define NHEAD 32
#define HDIM 128
#define SEQ 2048
#define BATCH 2
#define MROWS (BATCH * SEQ)      // 4096
#define QKVN (3 * HIDDEN_)       // 12288

typedef __bf16 bf16;
typedef __bf16 bf16x8 __attribute__((ext_vector_type(8)));
typedef float f32x4 __attribute__((ext_vector_type(4)));

#define AS1 __attribute__((address_space(1)))
#define AS3 __attribute__((address_space(3)))
#define PH_BAR do { asm volatile("" ::: "memory"); __builtin_amdgcn_s_barrier(); asm volatile("" ::: "memory"); } while (0)
#define MFMA_(d, a_, b_) (d) = __builtin_amdgcn_mfma_f32_16x16x32_bf16((a_), (b_), (d), 0, 0, 0)

// ---------------- cast fp32 -> bf16, 8 elems/thread ----------------
__global__ __launch_bounds__(256) void cast_bf16_k(const float* __restrict__ in,
                                                   bf16* __restrict__ out, int n) {
  int i = (blockIdx.x * 256 + threadIdx.x) * 8;
  if (i >= n) return;
  f32x4 a = *(const f32x4*)(in + i);
  f32x4 b = *(const f32x4*)(in + i + 4);
  bf16x8 o;
  o[0] = (bf16)a[0]; o[1] = (bf16)a[1]; o[2] = (bf16)a[2]; o[3] = (bf16)a[3];
  o[4] = (bf16)b[0]; o[5] = (bf16)b[1]; o[6] = (bf16)b[2]; o[7] = (bf16)b[3];
  *(bf16x8*)(out + i) = o;
}

// ---------------- transpose + cast: in[R][C] fp32 -> out[C][R] bf16 ----------------
__global__ __launch_bounds__(256) void transpose_cast_k(const float* __restrict__ in,
                                                        bf16* __restrict__ out,
                                                        int R, int C) {
  __shared__ float tile[32][33];
  int c0 = blockIdx.x * 32, r0 = blockIdx.y * 32;
  int tx = threadIdx.x & 31, ty = threadIdx.x >> 5;  // 32 x 8
#pragma unroll
  for (int i = 0; i < 4; i++) {
    int r = ty + i * 8;
    tile[r][tx] = in[(size_t)(r0 + r) * C + (c0 + tx)];
  }
  __syncthreads();
#pragma unroll
  for (int i = 0; i < 4; i++) {
    int r = ty + i * 8;
    out[(size_t)(c0 + r) * R + (r0 + tx)] = (bf16)tile[tx][r];
  }
}

// ---------------- 256x256 4-phase GEMM (round-7 best: ~394us, 0 conflicts) ----------------
// 512 threads = 8 waves (2M x 4N), per-wave C = 128x64, 16x16x32 MFMA, BK=64,
// 2 K-tiles/iter. LDS 128 KiB A0/A1/B0/B1 [256][64] bf16, XOR swizzle
// (byte ^= (row&7)<<4) via pre-swizzled global source + swizzled ds_read.
// 4 phases/iter, stages quarter-audited, vmcnt(4) at ph23/ph67.
template <int EPI>
__global__ __launch_bounds__(512, 2) void gemm256_k(
    const bf16* __restrict__ A, const bf16* __restrict__ BT,
    const float* __restrict__ bias, float* __restrict__ outF,
    bf16* __restrict__ Qb, bf16* __restrict__ Kb, bf16* __restrict__ Vt,
    int M, int N, int K, int nbx) {
  __shared__ char lds[131072];
  char* const A0 = lds;
  char* const A1 = lds + 32768;
  char* const B0 = lds + 65536;
  char* const B1 = lds + 98304;

  const int tid = threadIdx.x;
  const int w = tid >> 6, l = tid & 63;
  const int lg = l >> 4, cl = l & 15;
  const int wm = (w >> 2) * 128;
  const int wn = (w & 3) * 64;

  const int cpx = (int)gridDim.x >> 3;
  const int bid = blockIdx.x;
  const int swz = (bid & 7) * cpx + (bid >> 3);
  const int bx = swz % nbx, by = swz / nbx;
  const int m0 = by * 256, n0 = bx * 256;

  const int NT = K >> 6;
  const int NI = K >> 7;

  const bf16* gA[2][2]; const bf16* gB[2][2];
#pragma unroll
  for (int half = 0; half < 2; ++half)
#pragma unroll
    for (int i = 0; i < 2; ++i) {
      const int ci = i * 512 + tid;
      const int r = ci >> 3;
      const int cb = ((ci & 7) << 4) ^ ((r & 7) << 4);
      gA[half][i] = A + (size_t)(m0 + half * 128 + r) * K + (cb >> 1);
      gB[half][i] = BT + (size_t)(n0 + half * 128 + r) * K + (cb >> 1);
    }

  int offA[8][2], offB[4][2];
#pragma unroll
  for (int mf = 0; mf < 8; ++mf) {
    const int r = wm + mf * 16 + cl;
#pragma unroll
    for (int ks = 0; ks < 2; ++ks)
      offA[mf][ks] = r * 128 + ((ks * 64 + lg * 16) ^ ((r & 7) << 4));
  }
#pragma unroll
  for (int nf = 0; nf < 4; ++nf) {
    const int r = wn + nf * 16 + cl;
#pragma unroll
    for (int ks = 0; ks < 2; ++ks)
      offB[nf][ks] = r * 128 + ((ks * 64 + lg * 16) ^ ((r & 7) << 4));
  }

  auto stageA = [&](char* buf, int half, int kt) {
#pragma unroll
    for (int i = 0; i < 2; ++i) {
      const int ci = i * 512 + tid;
      __builtin_amdgcn_global_load_lds((const AS1 void*)(gA[half][i] + kt * 64),
                                       (AS3 void*)(buf + half * 16384 + ci * 16), 16, 0, 0);
    }
  };
  auto stageB = [&](char* buf, int half, int kt) {
#pragma unroll
    for (int i = 0; i < 2; ++i) {
      const int ci = i * 512 + tid;
      __builtin_amdgcn_global_load_lds((const AS1 void*)(gB[half][i] + kt * 64),
                                       (AS3 void*)(buf + half * 16384 + ci * 16), 16, 0, 0);
    }
  };
  auto rdA = [&](const char* buf, int mf, int ks) -> bf16x8 {
    return *(const bf16x8*)(buf + offA[mf][ks]);
  };
  auto rdB = [&](const char* buf, int nf, int ks) -> bf16x8 {
    return *(const bf16x8*)(buf + offB[nf][ks]);
  };

  f32x4 acc[8][4] = {};
  bf16x8 alo[4][2], ahi[4][2], blo[2][2], bhi[2][2];

  stageA(A0, 0, 0); stageB(B0, 0, 0); stageA(A0, 1, 0); stageB(B0, 1, 0);
  stageB(B1, 0, 1); stageB(B1, 1, 1);
  asm volatile("s_waitcnt vmcnt(4)" ::: "memory");
  PH_BAR;

  for (int j = 0; j < NI; ++j) {
    const int tw = 2 * j + 1;
    const int tu = (2 * j + 2) & (NT - 1);
    const int tv = (2 * j + 3) & (NT - 1);

    // ---- ph01: reads A0.lo + B0 all; stage A1<-tw; 32 MFMA ----
#pragma unroll
    for (int mf = 0; mf < 4; ++mf) { alo[mf][0] = rdA(A0, mf, 0); alo[mf][1] = rdA(A0, mf, 1); }
#pragma unroll
    for (int nf = 0; nf < 2; ++nf) { blo[nf][0] = rdB(B0, nf, 0); blo[nf][1] = rdB(B0, nf, 1); }
#pragma unroll
    for (int nf = 0; nf < 2; ++nf) { bhi[nf][0] = rdB(B0, 2 + nf, 0); bhi[nf][1] = rdB(B0, 2 + nf, 1); }
    stageA(A1, 0, tw);
    stageA(A1, 1, tw);
    __builtin_amdgcn_s_setprio(1);
#pragma unroll
    for (int mf = 0; mf < 4; ++mf)
#pragma unroll
      for (int nf = 0; nf < 2; ++nf)
#pragma unroll
        for (int ks = 0; ks < 2; ++ks) MFMA_(acc[mf][nf], alo[mf][ks], blo[nf][ks]);
#pragma unroll
    for (int mf = 0; mf < 4; ++mf)
#pragma unroll
      for (int nf = 0; nf < 2; ++nf)
#pragma unroll
        for (int ks = 0; ks < 2; ++ks) MFMA_(acc[mf][2 + nf], alo[mf][ks], bhi[nf][ks]);
    __builtin_amdgcn_s_setprio(0);
    PH_BAR;

    // ---- ph23: reads A0.hi; stage B0<-tu; 32 MFMA; vmcnt(4) drains tw ----
#pragma unroll
    for (int mf = 0; mf < 4; ++mf) { ahi[mf][0] = rdA(A0, 4 + mf, 0); ahi[mf][1] = rdA(A0, 4 + mf, 1); }
    stageB(B0, 0, tu);
    stageB(B0, 1, tu);
    __builtin_amdgcn_s_setprio(1);
#pragma unroll
    for (int mf = 0; mf < 4; ++mf)
#pragma unroll
      for (int nf = 0; nf < 2; ++nf)
#pragma unroll
        for (int ks = 0; ks < 2; ++ks) MFMA_(acc[4 + mf][2 + nf], ahi[mf][ks], bhi[nf][ks]);
#pragma unroll
    for (int mf = 0; mf < 4; ++mf)
#pragma unroll
      for (int nf = 0; nf < 2; ++nf)
#pragma unroll
        for (int ks = 0; ks < 2; ++ks) MFMA_(acc[4 + mf][nf], ahi[mf][ks], blo[nf][ks]);
    __builtin_amdgcn_s_setprio(0);
    asm volatile("s_waitcnt vmcnt(4)" ::: "memory");
    PH_BAR;

    // ---- ph45: reads A1.lo + B1 all; stage A0<-tu; 32 MFMA ----
#pragma unroll
    for (int mf = 0; mf < 4; ++mf) { alo[mf][0] = rdA(A1, mf, 0); alo[mf][1] = rdA(A1, mf, 1); }
#pragma unroll
    for (int nf = 0; nf < 2; ++nf) { blo[nf][0] = rdB(B1, nf, 0); blo[nf][1] = rdB(B1, nf, 1); }
#pragma unroll
    for (int nf = 0; nf < 2; ++nf) { bhi[nf][0] = rdB(B1, 2 + nf, 0); bhi[nf][1] = rdB(B1, 2 + nf, 1); }
    stageA(A0, 0, tu);
    stageA(A0, 1, tu);
    __builtin_amdgcn_s_setprio(1);
#pragma unroll
    for (int mf = 0; mf < 4; ++mf)
#pragma unroll
      for (int nf = 0; nf < 2; ++nf)
#pragma unroll
        for (int ks = 0; ks < 2; ++ks) MFMA_(acc[mf][nf], alo[mf][ks], blo[nf][ks]);
#pragma unroll
    for (int mf = 0; mf < 4; ++mf)
#pragma unroll
      for (int nf = 0; nf < 2; ++nf)
#pragma unroll
        for (int ks = 0; ks < 2; ++ks) MFMA_(acc[mf][2 + nf], alo[mf][ks], bhi[nf][ks]);
    __builtin_amdgcn_s_setprio(0);
    PH_BAR;

    // ---- ph67: reads A1.hi; stage B1<-tv; 32 MFMA; vmcnt(4) drains tu ----
#pragma unroll
    for (int mf = 0; mf < 4; ++mf) { ahi[mf][0] = rdA(A1, 4 + mf, 0); ahi[mf][1] = rdA(A1, 4 + mf, 1); }
    stageB(B1, 0, tv);
    stageB(B1, 1, tv);
    __builtin_amdgcn_s_setprio(1);
#pragma unroll
    for (int mf = 0; mf < 4; ++mf)
#pragma unroll
      for (int nf = 0; nf < 2; ++nf)
#pragma unroll
        for (int ks = 0; ks < 2; ++ks) MFMA_(acc[4 + mf][2 + nf], ahi[mf][ks], bhi[nf][ks]);
#pragma unroll
    for (int mf = 0; mf < 4; ++mf)
#pragma unroll
      for (int nf = 0; nf < 2; ++nf)
#pragma unroll
        for (int ks = 0; ks < 2; ++ks) MFMA_(acc[4 + mf][nf], ahi[mf][ks], blo[nf][ks]);
    __builtin_amdgcn_s_setprio(0);
    asm volatile("s_waitcnt vmcnt(4)" ::: "memory");
    PH_BAR;
  }

  // ---- epilogue: bias + store/scatter ----
#pragma unroll
  for (int mf = 0; mf < 8; ++mf) {
#pragma unroll
    for (int nf = 0; nf < 4; ++nf) {
      const int col = n0 + wn + nf * 16 + cl;
      const float bv = bias[col];
#pragma unroll
      for (int r = 0; r < 4; ++r) {
        const int row = m0 + wm + mf * 16 + lg * 4 + r;
        const float v = acc[mf][nf][r] + bv;
        if (EPI == 0) {
          const int which = col >> 12, rem = col & 4095;
          const int h = rem >> 7, d = rem & 127;
          const int b = row >> 11, s = row & 2047;
          const size_t bh = (size_t)b * NHEAD + h;
          if (which == 0)      Qb[(bh * SEQ + s) * HDIM + d] = (bf16)v;
          else if (which == 1) Kb[(bh * SEQ + s) * HDIM + d] = (bf16)v;
          else                 Vt[(bh * HDIM + d) * SEQ + s] = (bf16)v;
        } else {
          outF[(size_t)row * N + col] = v;
        }
      }
    }
  }
}

// ---------------- flash attention v3: 4 waves x 32 q-rows, 2x MFMA per LDS read ----------------
// grid = 16 qsteps * 64 bh (longest first), 256 threads. Block covers 128 q-rows;
// each wave owns 32 (two 16-row m-frags sharing every K/V fragment -> 32 MFMA per
// 16+16 LDS reads, halving read cost per FLOP). K [64][128] / V [128][64] dbuf
// staged via global_load_lds with XOR swizzle (rule 21); P per-wave 32x64 swizzled.
// LDS = 2*16 + 2*16 + 4*4 = 80 KB -> 2 blocks/CU.
__global__ __launch_bounds__(256, 2) void attn_k(const bf16* __restrict__ Qb,
                                                 const bf16* __restrict__ Kb,
                                                 const bf16* __restrict__ Vt,
                                                 bf16* __restrict__ ctx) {
  __shared__ bf16 Ks[2][64 * 128];   // 2 x 16 KB
  __shared__ bf16 Vs[2][128 * 64];   // 2 x 16 KB
  __shared__ bf16 Pl[4][32 * 64];    // 16 KB, per-wave P tile (swizzled)
  const int tid = threadIdx.x, w = tid >> 6, l = tid & 63;
  const int bid = blockIdx.x;
  const int qt = 15 - (bid >> 6);          // longest blocks first
  const int bh = bid & 63;
  const int h = bh & (NHEAD - 1), b = bh >> 5;
  const int qbase = qt * 128 + w * 32;     // wave owns rows qbase..qbase+31
  const int nt = 2 * qt + 2;
  const float slope = exp2f(-0.25f * (float)(h + 1));
  const float scale = 1.0f / 128.0f;
  const int lg = l >> 4, cl = l & 15;

  const bf16* Qp = Qb + (size_t)bh * SEQ * HDIM;
  const bf16* Kp = Kb + (size_t)bh * SEQ * HDIM;
  const bf16* Vp = Vt + (size_t)bh * HDIM * SEQ;
  char* plb = (char*)&Pl[w][0];

  // Q fragments for both 16-row m-frags
  bf16x8 qf[2][4];
#pragma unroll
  for (int mfr = 0; mfr < 2; ++mfr)
#pragma unroll
    for (int kb = 0; kb < 4; ++kb)
      qf[mfr][kb] = *(const bf16x8*)&Qp[(size_t)(qbase + mfr * 16 + cl) * HDIM + kb * 32 + lg * 8];

  float mi[2][4], li[2][4];
#pragma unroll
  for (int mfr = 0; mfr < 2; ++mfr)
#pragma unroll
    for (int r = 0; r < 4; ++r) { mi[mfr][r] = -3.0e38f; li[mfr][r] = 0.0f; }
  f32x4 oacc[2][8] = {};

  auto stage = [&](int buf, int t) {
    const int kv0 = t * 64;
#pragma unroll
    for (int i = 0; i < 4; i++) {
      const int ci = i * 256 + tid;  // 1024 chunks, 256 threads
      {  // K: 256B rows
        const int r = ci >> 4;
        const int cbl = ((ci & 15) << 4) ^ ((r & 7) << 4);
        const bf16* src = Kp + (size_t)(kv0 + r) * HDIM + (cbl >> 1);
        __builtin_amdgcn_global_load_lds(
            (const AS1 void*)src,
            (AS3 void*)((char*)&Ks[buf][0] + ci * 16), 16, 0, 0);
      }
      {  // V: 128B rows
        const int r = ci >> 3;
        const int cbl = ((ci & 7) << 4) ^ ((r & 7) << 4);
        const bf16* src = Vp + (size_t)r * SEQ + kv0 + (cbl >> 1);
        __builtin_amdgcn_global_load_lds(
            (const AS1 void*)src,
            (AS3 void*)((char*)&Vs[buf][0] + ci * 16), 16, 0, 0);
      }
    }
  };

  stage(0, 0);
  __syncthreads();

  for (int t = 0; t < nt; ++t) {
    const int cur = t & 1;
    if (t + 1 < nt) stage(cur ^ 1, t + 1);
    const int kv0 = t * 64;

    if (kv0 <= qbase + 31) {  // wave-uniform skip
      char* ksb = (char*)&Ks[cur][0];
      char* vsb = (char*)&Vs[cur][0];
      // ---- S = Q K^T: 16 kf reads feed 32 MFMA ----
      f32x4 sacc[2][4] = {};
      __builtin_amdgcn_s_setprio(1);
#pragma unroll
      for (int nb = 0; nb < 4; nb++) {
#pragma unroll
        for (int kb = 0; kb < 4; kb++) {
          const int row = nb * 16 + cl;
          const int cb = (kb * 64 + lg * 16) ^ ((row & 7) << 4);
          bf16x8 kf = *(const bf16x8*)(ksb + row * 256 + cb);
#pragma unroll
          for (int mfr = 0; mfr < 2; ++mfr)
            sacc[mfr][nb] = __builtin_amdgcn_mfma_f32_16x16x32_bf16(qf[mfr][kb], kf, sacc[mfr][nb], 0, 0, 0);
        }
      }
      __builtin_amdgcn_s_setprio(0);
      // ---- softmax per m-frag ----
#pragma unroll
      for (int mfr = 0; mfr < 2; ++mfr) {
        float pm[4];
#pragma unroll
        for (int r = 0; r < 4; r++) pm[r] = -3.0e38f;
#pragma unroll
        for (int nb = 0; nb < 4; nb++) {
          const int kv = kv0 + nb * 16 + cl;
#pragma unroll
          for (int r = 0; r < 4; r++) {
            const int q = qbase + mfr * 16 + lg * 4 + r;
            float v = sacc[mfr][nb][r] * scale + slope * (float)(kv - q);
            v = (kv <= q) ? v : -3.0e38f;
            sacc[mfr][nb][r] = v;
            pm[r] = fmaxf(pm[r], v);
          }
        }
#pragma unroll
        for (int r = 0; r < 4; r++) {
          pm[r] = fmaxf(pm[r], __shfl_xor(pm[r], 1));
          pm[r] = fmaxf(pm[r], __shfl_xor(pm[r], 2));
          pm[r] = fmaxf(pm[r], __shfl_xor(pm[r], 4));
          pm[r] = fmaxf(pm[r], __shfl_xor(pm[r], 8));
        }
        float alpha[4], rs[4];
#pragma unroll
        for (int r = 0; r < 4; r++) {
          const float nm = fmaxf(mi[mfr][r], pm[r]);
          alpha[r] = __expf(mi[mfr][r] - nm);
          mi[mfr][r] = nm;
          rs[r] = 0.0f;
        }
#pragma unroll
        for (int nb = 0; nb < 4; nb++) {
#pragma unroll
          for (int r = 0; r < 4; r++) {
            const float p = __expf(sacc[mfr][nb][r] - mi[mfr][r]);
            rs[r] += p;
            const int row = mfr * 16 + lg * 4 + r;
            *(bf16*)(plb + row * 128 + ((((nb * 16 + cl) << 1)) ^ ((row & 7) << 4))) = (bf16)p;
          }
        }
#pragma unroll
        for (int r = 0; r < 4; r++) {
          rs[r] += __shfl_xor(rs[r], 1);
          rs[r] += __shfl_xor(rs[r], 2);
          rs[r] += __shfl_xor(rs[r], 4);
          rs[r] += __shfl_xor(rs[r], 8);
          li[mfr][r] = li[mfr][r] * alpha[r] + rs[r];
        }
#pragma unroll
        for (int db = 0; db < 8; db++)
#pragma unroll
          for (int r = 0; r < 4; r++) oacc[mfr][db][r] *= alpha[r];
      }
      // ---- PV: 16 vf reads feed 32 MFMA ----
      bf16x8 pa[2][2];
#pragma unroll
      for (int mfr = 0; mfr < 2; ++mfr)
#pragma unroll
        for (int ks = 0; ks < 2; ks++) {
          const int cb = (ks * 64 + lg * 16) ^ ((cl & 7) << 4);
          pa[mfr][ks] = *(const bf16x8*)(plb + (mfr * 16 + cl) * 128 + cb);
        }
      __builtin_amdgcn_s_setprio(1);
#pragma unroll
      for (int db = 0; db < 8; db++) {
#pragma unroll
        for (int ks = 0; ks < 2; ks++) {
          const int row = db * 16 + cl;
          const int cb = (ks * 64 + lg * 16) ^ ((row & 7) << 4);
          bf16x8 vf = *(const bf16x8*)(vsb + row * 128 + cb);
#pragma unroll
          for (int mfr = 0; mfr < 2; ++mfr)
            oacc[mfr][db] = __builtin_amdgcn_mfma_f32_16x16x32_bf16(pa[mfr][ks], vf, oacc[mfr][db], 0, 0, 0);
        }
      }
      __builtin_amdgcn_s_setprio(0);
    }
    __syncthreads();
  }

  // ---- normalize + write ----
#pragma unroll
  for (int mfr = 0; mfr < 2; ++mfr) {
    float inv[4];
#pragma unroll
    for (int r = 0; r < 4; r++) inv[r] = 1.0f / li[mfr][r];
#pragma unroll
    for (int db = 0; db < 8; db++) {
#pragma unroll
      for (int r = 0; r < 4; r++) {
        const int q = qbase + mfr * 16 + lg * 4 + r;
        ctx[((size_t)(b * SEQ + q)) * HIDDEN_ + h * HDIM + db * 16 + cl] = (bf16)(oacc[mfr][db][r] * inv[r]);
      }
    }
  }
}

// ---------------- launcher ----------------
extern "C" void kernel_launch(void* const* d_in, const int* in_sizes, int n_in,
                              void* d_out, int out_size, void* d_ws, size_t ws_size,
                              hipStream_t stream) {
  const float* hs     = (const float*)d_in[0];
  const float* w_attn = (const float*)d_in[1];
  const float* b_attn = (const float*)d_in[2];
  const float* w_proj = (const float*)d_in[3];
  const float* b_proj = (const float*)d_in[4];
  float* out = (float*)d_out;

  char* ws = (char*)d_ws;
  bf16* Xb  = (bf16*)(ws + 0);           // [4096][4096]        33.5 MB
  bf16* WaT = (bf16*)(ws + 33554432);    // [12288][4096]      100.7 MB
  bf16* WpT = (bf16*)(ws + 134217728);   // [4096][4096]        33.5 MB
  bf16* Qb  = (bf16*)(ws + 167772160);   // [B,H,S,D]           33.5 MB
  bf16* Kb  = (bf16*)(ws + 201326592);   // [B,H,S,D]           33.5 MB
  bf16* Vt  = (bf16*)(ws + 234881024);   // [B,H,D,S]           33.5 MB
  bf16* ctx = (bf16*)(ws + 268435456);   // [4096][4096]        33.5 MB

  cast_bf16_k<<<(MROWS * HIDDEN_) / (256 * 8), 256, 0, stream>>>(hs, Xb, MROWS * HIDDEN_);
  transpose_cast_k<<<dim3(QKVN / 32, HIDDEN_ / 32), 256, 0, stream>>>(w_attn, WaT, HIDDEN_, QKVN);
  transpose_cast_k<<<dim3(HIDDEN_ / 32, HIDDEN_ / 32), 256, 0, stream>>>(w_proj, WpT, HIDDEN_, HIDDEN_);

  gemm256_k<0><<<dim3((QKVN / 256) * (MROWS / 256)), 512, 0, stream>>>(
      Xb, WaT, b_attn, nullptr, Qb, Kb, Vt, MROWS, QKVN, HIDDEN_, QKVN / 256);

  attn_k<<<16 * 64, 256, 0, stream>>>(Qb, Kb, Vt, ctx);

  gemm256_k<1><<<dim3((HIDDEN_ / 256) * (MROWS / 256)), 512, 0, stream>>>(
      ctx, WpT, b_proj, out, nullptr, nullptr, nullptr, MROWS, HIDDEN_, HIDDEN_, HIDDEN_ / 256);
}